// Round 7
// baseline (33.948 us; speedup 1.0000x reference)
//
#include <hip/hip_runtime.h>
#include <math.h>

// Problem constants (from reference setup_inputs)
#define BB 16
#define QQ 900
#define NC 92
#define NCP 96          // padded class count (cols 92..95 = 0)
#define TT 1600
#define BQ (BB * QQ)    // 14400

// ---------------------------------------------------------------------------
// R7: fused cost kernel, event-count-reduced.
//   grid = (BQ/8 = 1800, 1), block = 256 = 4 waves.
//   Wave rg owns RT=2 rows; each lane handles 2 ADJACENT targets per iter
//   -> float2 stores (512 B/wave-instr), 12 pair-iters + 1 scalar tail.
//   LDS: probs transposed pg[class][row] (stride 10 floats) so ONE
//   ds_read_b64 fetches both of the wave's rows for a target id.
// ---------------------------------------------------------------------------
#define RT 2        // rows per thread (= rows per wave)
#define RTILE 8     // rows per block
#define NKP 12      // pair iterations: 12 * 128 = 1536 targets, then 64 tail

__global__ __launch_bounds__(256)
void k_cost(const float* __restrict__ logits,
            const float* __restrict__ boxes,       // [BQ,4] cxcywh
            const int* __restrict__ tids,          // [TT] int32
            const float* __restrict__ tbox,        // [TT,4] cxcywh
            float* __restrict__ out) {
    __shared__ float pg[NCP][10];                  // [class][row], 3840 B

    const int row0 = blockIdx.x * RTILE;

    // ---- stage unnormalized exp(logit), transposed; cols 92..95 = 0 ----
    #pragma unroll
    for (int it = 0; it < 3; ++it) {               // 3 x 256 = 768 = 8*96
        int idx = it * 256 + threadIdx.x;
        int r = idx / NCP, c = idx - r * NCP;      // consecutive tid -> c fast
        float v = 0.0f;
        if (c < NC) v = __expf(logits[(row0 + r) * NC + c]);
        pg[c][r] = v;
    }
    __syncthreads();

    // ---- normalize in place: thread owns (row r, cols 3ls..3ls+2) ----
    {
        const int r  = threadIdx.x >> 5;           // 0..7
        const int ls = threadIdx.x & 31;           // 0..31 (3*31+2 = 95)
        float a = pg[ls * 3][r];
        float b = pg[ls * 3 + 1][r];
        float d = pg[ls * 3 + 2][r];
        float s = a + b + d;
        s += __shfl_xor(s, 1);
        s += __shfl_xor(s, 2);
        s += __shfl_xor(s, 4);
        s += __shfl_xor(s, 8);
        s += __shfl_xor(s, 16);                    // sum over 32-lane half
        float rinv = __builtin_amdgcn_rcpf(s);
        pg[ls * 3][r]     = a * rinv;
        pg[ls * 3 + 1][r] = b * rinv;
        pg[ls * 3 + 2][r] = d * rinv;
    }

    const int tl   = threadIdx.x & 63;
    const int rg   = threadIdx.x >> 6;
    const int rloc = rg * RT;                      // 0,2,4,6
    const int rbase = row0 + rloc;

    // ---- register-blocked row box data ----
    float rcx[RT], rcy[RT], rw[RT], rh[RT];
    float rx0[RT], ry0[RT], rx1[RT], ry1[RT], rar[RT];
    #pragma unroll
    for (int j = 0; j < RT; ++j) {
        float4 bb = ((const float4*)boxes)[rbase + j];
        rcx[j] = bb.x; rcy[j] = bb.y; rw[j] = bb.z; rh[j] = bb.w;
        rx0[j] = bb.x - 0.5f * bb.z; ry0[j] = bb.y - 0.5f * bb.w;
        rx1[j] = bb.x + 0.5f * bb.z; ry1[j] = bb.y + 0.5f * bb.w;
        rar[j] = bb.z * bb.w;
    }
    __syncthreads();

    const float4* tb4 = (const float4*)tbox;
    const int2*   id2 = (const int2*)tids;

    // ---- main loop: 12 iters x 128 targets (2 per lane, adjacent) ----
    #pragma unroll 4
    for (int k = 0; k < NKP; ++k) {
        const int tp = k * 64 + tl;                // pair index
        float4 ta = tb4[tp * 2];                   // target 2*tp
        float4 tc = tb4[tp * 2 + 1];               // target 2*tp+1
        int2   ii = id2[tp];
        // prob pairs for both rows of this wave (b64 each)
        float2 pa = *(const float2*)&pg[ii.x][rloc];
        float2 pc = *(const float2*)&pg[ii.y][rloc];

        float ax0 = ta.x - 0.5f * ta.z, ay0 = ta.y - 0.5f * ta.w;
        float ax1 = ta.x + 0.5f * ta.z, ay1 = ta.y + 0.5f * ta.w;
        float aar = ta.z * ta.w;
        float cx0 = tc.x - 0.5f * tc.z, cy0 = tc.y - 0.5f * tc.w;
        float cx1 = tc.x + 0.5f * tc.z, cy1 = tc.y + 0.5f * tc.w;
        float car = tc.z * tc.w;

        #pragma unroll
        for (int j = 0; j < RT; ++j) {
            float2 o;
            {   // target a
                float l1 = fabsf(rcx[j] - ta.x) + fabsf(rcy[j] - ta.y)
                         + fabsf(rw[j]  - ta.z) + fabsf(rh[j]  - ta.w);
                float iwu = fminf(rx1[j], ax1) - fmaxf(rx0[j], ax0);
                float ihu = fminf(ry1[j], ay1) - fmaxf(ry0[j], ay0);
                float inter = fmaxf(iwu, 0.0f) * fmaxf(ihu, 0.0f);
                float uni = rar[j] + aar - inter;
                float ew = (rw[j] + ta.z) - iwu;
                float eh = (rh[j] + ta.w) - ihu;
                float ea = ew * eh;
                float num = fmaf(ea, inter - uni, uni * uni);
                float rden = __builtin_amdgcn_rcpf(uni * ea);
                float p = (j == 0) ? pa.x : pa.y;
                float c = fmaf(5.0f, l1, -p);
                o.x = fmaf(-2.0f * num, rden, c);
            }
            {   // target c
                float l1 = fabsf(rcx[j] - tc.x) + fabsf(rcy[j] - tc.y)
                         + fabsf(rw[j]  - tc.z) + fabsf(rh[j]  - tc.w);
                float iwu = fminf(rx1[j], cx1) - fmaxf(rx0[j], cx0);
                float ihu = fminf(ry1[j], cy1) - fmaxf(ry0[j], cy0);
                float inter = fmaxf(iwu, 0.0f) * fmaxf(ihu, 0.0f);
                float uni = rar[j] + car - inter;
                float ew = (rw[j] + tc.z) - iwu;
                float eh = (rh[j] + tc.w) - ihu;
                float ea = ew * eh;
                float num = fmaf(ea, inter - uni, uni * uni);
                float rden = __builtin_amdgcn_rcpf(uni * ea);
                float p = (j == 0) ? pc.x : pc.y;
                float c = fmaf(5.0f, l1, -p);
                o.y = fmaf(-2.0f * num, rden, c);
            }
            *(float2*)&out[(rbase + j) * TT + tp * 2] = o;
        }
    }

    // ---- tail: targets 1536..1599, one per lane ----
    {
        const int t = NKP * 128 + tl;
        float4 tb = tb4[t];
        int    id = tids[t];
        float2 pt = *(const float2*)&pg[id][rloc];
        float tx0 = tb.x - 0.5f * tb.z, ty0 = tb.y - 0.5f * tb.w;
        float tx1 = tb.x + 0.5f * tb.z, ty1 = tb.y + 0.5f * tb.w;
        float tar = tb.z * tb.w;
        #pragma unroll
        for (int j = 0; j < RT; ++j) {
            float l1 = fabsf(rcx[j] - tb.x) + fabsf(rcy[j] - tb.y)
                     + fabsf(rw[j]  - tb.z) + fabsf(rh[j]  - tb.w);
            float iwu = fminf(rx1[j], tx1) - fmaxf(rx0[j], tx0);
            float ihu = fminf(ry1[j], ty1) - fmaxf(ry0[j], ty0);
            float inter = fmaxf(iwu, 0.0f) * fmaxf(ihu, 0.0f);
            float uni = rar[j] + tar - inter;
            float ew = (rw[j] + tb.z) - iwu;
            float eh = (rh[j] + tb.w) - ihu;
            float ea = ew * eh;
            float num = fmaf(ea, inter - uni, uni * uni);
            float rden = __builtin_amdgcn_rcpf(uni * ea);
            float p = (j == 0) ? pt.x : pt.y;
            float c = fmaf(5.0f, l1, -p);
            c = fmaf(-2.0f * num, rden, c);
            out[(rbase + j) * TT + t] = c;
        }
    }
}

// ---------------------------------------------------------------------------
extern "C" void kernel_launch(void* const* d_in, const int* in_sizes, int n_in,
                              void* d_out, int out_size, void* d_ws, size_t ws_size,
                              hipStream_t stream) {
    const float* logits = (const float*)d_in[0];   // [16,900,92] f32
    const float* boxes  = (const float*)d_in[1];   // [16,900,4]  f32
    const int*   tids   = (const int*)  d_in[2];   // [1600] int32
    const float* tbox   = (const float*)d_in[3];   // [1600,4] f32
    float* out = (float*)d_out;

    k_cost<<<dim3(BQ / RTILE, 1), 256, 0, stream>>>(
        logits, boxes, tids, tbox, out);
}

// Round 8
// 28.478 us; speedup vs baseline: 1.1921x; 1.1921x over previous
//
#include <hip/hip_runtime.h>
#include <math.h>

// Problem constants (from reference setup_inputs)
#define BB 16
#define QQ 900
#define NC 92
#define NCP 96          // padded LDS row
#define TT 1600
#define BQ (BB * QQ)    // 14400

// ---------------------------------------------------------------------------
// R8: R6 structure + LDS-staged float4 output flush.
//   grid = (BQ/8 = 1800, 1), block = 256 = 4 waves.
//   Wave rg owns RT=2 rows; 64 lanes sweep all 1600 targets.
//   24 iters in groups of 4: outputs -> per-wave LDS tile -> dwordx4 flush
//   (1 KB contiguous per store instr, 2 instrs per 4 iters vs 8 dword
//   stores). +1 tail iter with direct dword stores.
//   Tile is wave-private: no __syncthreads needed around it.
// ---------------------------------------------------------------------------
#define RT 2        // rows per thread (= rows per wave)
#define RTILE 8     // rows per block
#define NKB 6       // 6 groups x 4 iters x 64 targets = 1536, + 64 tail

__global__ __launch_bounds__(256)
void k_cost(const float* __restrict__ logits,
            const float* __restrict__ boxes,       // [BQ,4] cxcywh
            const int* __restrict__ tids,          // [TT] int32
            const float* __restrict__ tbox,        // [TT,4] cxcywh
            float* __restrict__ out) {
    __shared__ float pexp[RTILE][NCP];             // 3072 B
    __shared__ float tile[4][RT][256];             // 8192 B (per-wave private)

    const int row0 = blockIdx.x * RTILE;

    // ---- stage unnormalized exp(logit) via float2; pad cols 92..95 = 0 ----
    {
        int idx = threadIdx.x * 2;
        int r = idx / NCP, c = idx - r * NCP;
        float2 v = make_float2(0.0f, 0.0f);
        if (c < NC) {
            float2 lv = *(const float2*)&logits[(row0 + r) * NC + c];
            v.x = __expf(lv.x); v.y = __expf(lv.y);
        }
        *(float2*)&pexp[r][c] = v;
        if (threadIdx.x < 128) {
            int idx2 = 512 + threadIdx.x * 2;
            int r2 = idx2 / NCP, c2 = idx2 - r2 * NCP;
            float2 v2 = make_float2(0.0f, 0.0f);
            if (c2 < NC) {
                float2 lv = *(const float2*)&logits[(row0 + r2) * NC + c2];
                v2.x = __expf(lv.x); v2.y = __expf(lv.y);
            }
            *(float2*)&pexp[r2][c2] = v2;
        }
    }
    __syncthreads();

    // ---- normalize LDS probs in place (stride-3 cols, conflict-free) ----
    {
        const int r  = threadIdx.x >> 5;           // 0..7
        const int ls = threadIdx.x & 31;           // 0..31
        float a = pexp[r][ls * 3];
        float b = pexp[r][ls * 3 + 1];
        float d = pexp[r][ls * 3 + 2];
        float s = a + b + d;
        s += __shfl_xor(s, 1);
        s += __shfl_xor(s, 2);
        s += __shfl_xor(s, 4);
        s += __shfl_xor(s, 8);
        s += __shfl_xor(s, 16);
        float rinv = __builtin_amdgcn_rcpf(s);
        pexp[r][ls * 3]     = a * rinv;
        pexp[r][ls * 3 + 1] = b * rinv;
        pexp[r][ls * 3 + 2] = d * rinv;
    }

    const int tl   = threadIdx.x & 63;
    const int rg   = threadIdx.x >> 6;
    const int rloc = rg * RT;
    const int rbase = row0 + rloc;

    // ---- register-blocked row box data ----
    float rcx[RT], rcy[RT], rw[RT], rh[RT];
    float rx0[RT], ry0[RT], rx1[RT], ry1[RT], rar[RT];
    #pragma unroll
    for (int j = 0; j < RT; ++j) {
        float4 bb = ((const float4*)boxes)[rbase + j];
        rcx[j] = bb.x; rcy[j] = bb.y; rw[j] = bb.z; rh[j] = bb.w;
        rx0[j] = bb.x - 0.5f * bb.z; ry0[j] = bb.y - 0.5f * bb.w;
        rx1[j] = bb.x + 0.5f * bb.z; ry1[j] = bb.y + 0.5f * bb.w;
        rar[j] = bb.z * bb.w;
    }
    __syncthreads();

    // ---- main loop: 6 groups of 4 iters, LDS-staged, float4 flush ----
    float4 tb = ((const float4*)tbox)[tl];
    int    id = tids[tl];
    for (int kb = 0; kb < NKB; ++kb) {
        #pragma unroll
        for (int ki = 0; ki < 4; ++ki) {
            const int k = kb * 4 + ki;
            // prefetch next iteration's target data
            float4 tbn; int idn;
            {
                const int tn = (k + 1) * 64 + tl;   // k+1 <= 24 always valid
                tbn = ((const float4*)tbox)[tn];
                idn = tids[tn];
            }
            float tx0 = tb.x - 0.5f * tb.z, ty0 = tb.y - 0.5f * tb.w;
            float tx1 = tb.x + 0.5f * tb.z, ty1 = tb.y + 0.5f * tb.w;
            float tar = tb.z * tb.w;
            #pragma unroll
            for (int j = 0; j < RT; ++j) {
                float l1 = fabsf(rcx[j] - tb.x) + fabsf(rcy[j] - tb.y)
                         + fabsf(rw[j]  - tb.z) + fabsf(rh[j]  - tb.w);
                float iwu = fminf(rx1[j], tx1) - fmaxf(rx0[j], tx0);
                float ihu = fminf(ry1[j], ty1) - fmaxf(ry0[j], ty0);
                float inter = fmaxf(iwu, 0.0f) * fmaxf(ihu, 0.0f);
                float uni = rar[j] + tar - inter;
                float ew = (rw[j] + tb.z) - iwu;
                float eh = (rh[j] + tb.w) - ihu;
                float ea = ew * eh;
                float num = fmaf(ea, inter - uni, uni * uni);
                float rden = __builtin_amdgcn_rcpf(uni * ea);
                float p = pexp[rloc + j][id];
                float c = fmaf(5.0f, l1, -p);
                c = fmaf(-2.0f * num, rden, c);
                tile[rg][j][ki * 64 + tl] = c;
            }
            tb = tbn; id = idn;
        }
        // flush group: 2 float4 stores per lane-set (1 KB contiguous each)
        const int tg = kb * 256;
        #pragma unroll
        for (int r = 0; r < RT; ++r) {
            float4 v = *(const float4*)&tile[rg][r][tl * 4];
            *(float4*)&out[(rbase + r) * TT + tg + tl * 4] = v;
        }
    }

    // ---- tail: targets 1536..1599 (tb/id already hold k=24 data) ----
    {
        const int t = 24 * 64 + tl;
        float tx0 = tb.x - 0.5f * tb.z, ty0 = tb.y - 0.5f * tb.w;
        float tx1 = tb.x + 0.5f * tb.z, ty1 = tb.y + 0.5f * tb.w;
        float tar = tb.z * tb.w;
        #pragma unroll
        for (int j = 0; j < RT; ++j) {
            float l1 = fabsf(rcx[j] - tb.x) + fabsf(rcy[j] - tb.y)
                     + fabsf(rw[j]  - tb.z) + fabsf(rh[j]  - tb.w);
            float iwu = fminf(rx1[j], tx1) - fmaxf(rx0[j], tx0);
            float ihu = fminf(ry1[j], ty1) - fmaxf(ry0[j], ty0);
            float inter = fmaxf(iwu, 0.0f) * fmaxf(ihu, 0.0f);
            float uni = rar[j] + tar - inter;
            float ew = (rw[j] + tb.z) - iwu;
            float eh = (rh[j] + tb.w) - ihu;
            float ea = ew * eh;
            float num = fmaf(ea, inter - uni, uni * uni);
            float rden = __builtin_amdgcn_rcpf(uni * ea);
            float p = pexp[rloc + j][id];
            float c = fmaf(5.0f, l1, -p);
            c = fmaf(-2.0f * num, rden, c);
            out[(rbase + j) * TT + t] = c;
        }
    }
}

// ---------------------------------------------------------------------------
extern "C" void kernel_launch(void* const* d_in, const int* in_sizes, int n_in,
                              void* d_out, int out_size, void* d_ws, size_t ws_size,
                              hipStream_t stream) {
    const float* logits = (const float*)d_in[0];   // [16,900,92] f32
    const float* boxes  = (const float*)d_in[1];   // [16,900,4]  f32
    const int*   tids   = (const int*)  d_in[2];   // [1600] int32
    const float* tbox   = (const float*)d_in[3];   // [1600,4] f32
    float* out = (float*)d_out;

    k_cost<<<dim3(BQ / RTILE, 1), 256, 0, stream>>>(
        logits, boxes, tids, tbox, out);
}